// Round 1
// baseline (460.608 us; speedup 1.0000x reference)
//
#include <hip/hip_runtime.h>
#include <hip/hip_bf16.h>

#define BN_EPS 1e-5f

// ---------------- CSR build ----------------

__global__ __launch_bounds__(256) void k_init_counts(int* __restrict__ cnt, int n) {
  int i = blockIdx.x * 256 + threadIdx.x;
  if (i < n) cnt[i] = 1;  // self-loop pre-count
}

__global__ __launch_bounds__(256) void k_hist(const int* __restrict__ ei, int* __restrict__ cnt, int E) {
  int i = blockIdx.x * 256 + threadIdx.x;
  if (i < E) atomicAdd(&cnt[ei[E + i]], 1);  // dst row
}

__global__ __launch_bounds__(256) void k_scan1(const int* __restrict__ cnt, int* __restrict__ offs,
                                               int* __restrict__ bsum, int n) {
  __shared__ int sm[256];
  int tid = threadIdx.x;
  int i = blockIdx.x * 256 + tid;
  int v = (i < n) ? cnt[i] : 0;
  sm[tid] = v;
  __syncthreads();
  #pragma unroll
  for (int off = 1; off < 256; off <<= 1) {
    int t = sm[tid];
    int u = (tid >= off) ? sm[tid - off] : 0;
    __syncthreads();
    sm[tid] = t + u;
    __syncthreads();
  }
  int incl = sm[tid];
  if (i < n) offs[i] = incl - v;          // block-local exclusive
  if (tid == 255) bsum[blockIdx.x] = incl;  // block total
}

__global__ __launch_bounds__(256) void k_scan2(int* __restrict__ bsum, int nb) {
  __shared__ int sm[256];
  int tid = threadIdx.x;
  int v = (tid < nb) ? bsum[tid] : 0;
  sm[tid] = v;
  __syncthreads();
  #pragma unroll
  for (int off = 1; off < 256; off <<= 1) {
    int t = sm[tid];
    int u = (tid >= off) ? sm[tid - off] : 0;
    __syncthreads();
    sm[tid] = t + u;
    __syncthreads();
  }
  if (tid < nb) bsum[tid] = sm[tid] - v;  // exclusive
}

__global__ __launch_bounds__(256) void k_scan3(int* __restrict__ offs, int* __restrict__ cursor,
                                               const int* __restrict__ bsum, int n, int etot) {
  int i = blockIdx.x * 256 + threadIdx.x;
  if (i < n) {
    int o = offs[i] + bsum[i >> 8];
    offs[i] = o;
    cursor[i] = o;
  } else if (i == n) {
    offs[n] = etot;
  }
}

__global__ __launch_bounds__(256) void k_scatter(const int* __restrict__ ei, int* __restrict__ cursor,
                                                 int* __restrict__ csr, int E, int n) {
  int i = blockIdx.x * 256 + threadIdx.x;
  int etot = E + n;
  if (i >= etot) return;
  int s, d;
  if (i < E) { s = ei[i]; d = ei[E + i]; }
  else       { s = i - E; d = s; }        // self-loop
  int pos = atomicAdd(&cursor[d], 1);
  csr[pos] = s;
}

// ---------------- dense: h = X @ W, plus attention logit dots ----------------

template<int K, int FOUT, int HEADS>
__global__ __launch_bounds__(256) void k_gemm(const float* __restrict__ X,
    const float* __restrict__ W, const float* __restrict__ a_s, const float* __restrict__ a_d,
    float* __restrict__ Hout, float* __restrict__ als, float* __restrict__ ald, int n) {
  __shared__ float Wl[K * FOUT];
  int tid = threadIdx.x;
  for (int idx = tid; idx < K * FOUT; idx += 256) Wl[idx] = W[idx];
  __syncthreads();
  constexpr int NPT = 16;
  constexpr int SUBS = 256 / FOUT;
  int base = blockIdx.x * NPT;
  int col = tid % FOUT;
  int sub = tid / FOUT;
  int head = col >> 5;
  int dd = col & 31;
  float asc = a_s[head * 32 + dd];
  float adc = a_d[head * 32 + dd];
  for (int i = sub; i < NPT; i += SUBS) {
    int row = base + i;
    if (row >= n) break;
    const float* xr = X + (size_t)row * K;
    float acc0 = 0.f, acc1 = 0.f, acc2 = 0.f, acc3 = 0.f;
    #pragma unroll
    for (int k = 0; k < K; k += 4) {
      acc0 += xr[k]     * Wl[(k)     * FOUT + col];
      acc1 += xr[k + 1] * Wl[(k + 1) * FOUT + col];
      acc2 += xr[k + 2] * Wl[(k + 2) * FOUT + col];
      acc3 += xr[k + 3] * Wl[(k + 3) * FOUT + col];
    }
    float acc = (acc0 + acc1) + (acc2 + acc3);
    Hout[(size_t)row * FOUT + col] = acc;
    float s = acc * asc, t = acc * adc;
    #pragma unroll
    for (int off = 16; off; off >>= 1) {
      s += __shfl_down(s, off, 32);
      t += __shfl_down(t, off, 32);
    }
    if (dd == 0) {
      als[row * HEADS + head] = s;
      ald[row * HEADS + head] = t;
    }
  }
}

// ---------------- fused edge-softmax + aggregate + bias + BN + ELU ----------------
// one wave per dst node; CSR-gather, no atomics.

template<int HEADS, int FEAT>
__global__ __launch_bounds__(256) void k_agg(const int* __restrict__ offs, const int* __restrict__ csr,
    const float* __restrict__ Hb, const float* __restrict__ als, const float* __restrict__ ald,
    const float* __restrict__ bias, const float* __restrict__ gam, const float* __restrict__ bet,
    const float* __restrict__ mu, const float* __restrict__ var,
    float* __restrict__ Xo, int n) {
  constexpr int LPF = FEAT / 4;   // lanes covering the features (float4 each): 32 or 8
  constexpr int EPW = 64 / LPF;   // edges in flight per wave: 2 or 8
  int wv = (blockIdx.x * 256 + threadIdx.x) >> 6;
  if (wv >= n) return;
  int lane = threadIdx.x & 63;
  int rs = offs[wv], re = offs[wv + 1];

  // phase 1: denominators per head (edge-parallel over lanes)
  float aldv[HEADS];
  #pragma unroll
  for (int h = 0; h < HEADS; ++h) aldv[h] = ald[wv * HEADS + h];
  float den[HEADS];
  #pragma unroll
  for (int h = 0; h < HEADS; ++h) den[h] = 0.f;
  for (int j = rs + lane; j < re; j += 64) {
    int s = csr[j];
    #pragma unroll
    for (int h = 0; h < HEADS; ++h) {
      float e = als[s * HEADS + h] + aldv[h];
      e = (e > 0.f) ? e : 0.2f * e;       // leaky_relu 0.2
      den[h] += __expf(e);
    }
  }
  #pragma unroll
  for (int h = 0; h < HEADS; ++h) {
    float vv = den[h];
    #pragma unroll
    for (int off = 32; off; off >>= 1) vv += __shfl_xor(vv, off, 64);
    den[h] = vv;
  }

  // per-lane head / feature assignment
  int fl = lane % LPF;
  int ei = lane / LPF;
  int f0 = fl * 4;
  int myh = (HEADS == 4) ? (f0 >> 5) : 0;
  float mden = den[0];
  if (HEADS == 4)
    mden = (myh == 0) ? den[0] : ((myh == 1) ? den[1] : ((myh == 2) ? den[2] : den[3]));
  float myinv = 1.f / (mden + 1e-16f);
  float myald = ald[wv * HEADS + myh];

  // phase 2: feature-parallel weighted gather, EPW edges in flight
  float a0 = 0.f, a1 = 0.f, a2 = 0.f, a3 = 0.f;
  for (int j = rs; j < re; j += EPW) {
    int jj = j + ei;
    if (jj < re) {
      int s = csr[jj];
      float e = als[s * HEADS + myh] + myald;
      e = (e > 0.f) ? e : 0.2f * e;
      float alpha = __expf(e) * myinv;
      float4 hv = *(const float4*)(Hb + (size_t)s * FEAT + f0);
      a0 += alpha * hv.x; a1 += alpha * hv.y; a2 += alpha * hv.z; a3 += alpha * hv.w;
    }
  }
  #pragma unroll
  for (int off = 32; off >= LPF; off >>= 1) {
    a0 += __shfl_xor(a0, off, 64);
    a1 += __shfl_xor(a1, off, 64);
    a2 += __shfl_xor(a2, off, 64);
    a3 += __shfl_xor(a3, off, 64);
  }

  if (lane < LPF) {
    float4 o;
    float av[4] = {a0, a1, a2, a3};
    float ov[4];
    #pragma unroll
    for (int q = 0; q < 4; ++q) {
      int f = f0 + q;
      float xo = av[q] + bias[f];
      xo = (xo - mu[f]) * rsqrtf(var[f] + BN_EPS) * gam[f] + bet[f];
      ov[q] = (xo > 0.f) ? xo : (__expf(xo) - 1.f);  // ELU
    }
    o.x = ov[0]; o.y = ov[1]; o.z = ov[2]; o.w = ov[3];
    *(float4*)(Xo + (size_t)wv * FEAT + f0) = o;
  }
}

// ---------------- classifier: Linear(32->16) -> ReLU -> Linear(16->1) -> sigmoid ----------------

__global__ __launch_bounds__(256) void k_cls(const float* __restrict__ X3,
    const float* __restrict__ cW1, const float* __restrict__ cb1,
    const float* __restrict__ cW2, const float* __restrict__ cb2,
    float* __restrict__ out, int n) {
  int i = blockIdx.x * 256 + threadIdx.x;
  if (i >= n) return;
  float x[32];
  #pragma unroll
  for (int k = 0; k < 32; k += 4) {
    float4 v = *(const float4*)&X3[(size_t)i * 32 + k];
    x[k] = v.x; x[k + 1] = v.y; x[k + 2] = v.z; x[k + 3] = v.w;
  }
  float o = cb2[0];
  #pragma unroll
  for (int j = 0; j < 16; ++j) {
    float hs = cb1[j];
    #pragma unroll
    for (int k = 0; k < 32; ++k) hs += x[k] * cW1[k * 16 + j];
    hs = fmaxf(hs, 0.f);
    o += hs * cW2[j];
  }
  out[i] = 1.f / (1.f + __expf(-o));
}

// ---------------- host ----------------

static inline size_t align256(size_t x) { return (x + 255) & ~(size_t)255; }

extern "C" void kernel_launch(void* const* d_in, const int* in_sizes, int n_in,
                              void* d_out, int out_size, void* d_ws, size_t ws_size,
                              hipStream_t stream) {
  const float* x   = (const float*)d_in[0];
  const int*   ei  = (const int*)d_in[1];
  const float* W1  = (const float*)d_in[2];
  const float* as1 = (const float*)d_in[3];
  const float* ad1 = (const float*)d_in[4];
  const float* b1  = (const float*)d_in[5];
  const float* g1  = (const float*)d_in[6];
  const float* be1 = (const float*)d_in[7];
  const float* m1  = (const float*)d_in[8];
  const float* v1  = (const float*)d_in[9];
  const float* W2  = (const float*)d_in[10];
  const float* as2 = (const float*)d_in[11];
  const float* ad2 = (const float*)d_in[12];
  const float* b2  = (const float*)d_in[13];
  const float* g2  = (const float*)d_in[14];
  const float* be2 = (const float*)d_in[15];
  const float* m2  = (const float*)d_in[16];
  const float* v2  = (const float*)d_in[17];
  const float* W3  = (const float*)d_in[18];
  const float* as3 = (const float*)d_in[19];
  const float* ad3 = (const float*)d_in[20];
  const float* b3  = (const float*)d_in[21];
  const float* g3  = (const float*)d_in[22];
  const float* be3 = (const float*)d_in[23];
  const float* m3  = (const float*)d_in[24];
  const float* v3  = (const float*)d_in[25];
  const float* cW1 = (const float*)d_in[26];
  const float* cb1 = (const float*)d_in[27];
  const float* cW2 = (const float*)d_in[28];
  const float* cb2 = (const float*)d_in[29];

  const int n = in_sizes[0] / 8;
  const int E = in_sizes[1] / 2;
  const int etot = E + n;
  const int nb1 = (n + 255) / 256;

  // workspace carve
  char* p = (char*)d_ws;
  int* cursor = (int*)p;  p += align256((size_t)(n + 1) * 4);
  int* offs   = (int*)p;  p += align256((size_t)(n + 1) * 4);
  int* csr    = (int*)p;  p += align256((size_t)etot * 4);
  int* bsum   = (int*)p;  p += align256(1024);
  float* als  = (float*)p; p += align256((size_t)n * 4 * 4);
  float* ald  = (float*)p; p += align256((size_t)n * 4 * 4);
  float* bufA = (float*)p; p += align256((size_t)n * 128 * 4);
  float* bufB = (float*)p; p += align256((size_t)n * 128 * 4);

  // CSR build
  k_init_counts<<<nb1, 256, 0, stream>>>(cursor, n);
  k_hist<<<(E + 255) / 256, 256, 0, stream>>>(ei, cursor, E);
  k_scan1<<<nb1, 256, 0, stream>>>(cursor, offs, bsum, n);
  k_scan2<<<1, 256, 0, stream>>>(bsum, nb1);
  k_scan3<<<(n + 1 + 255) / 256, 256, 0, stream>>>(offs, cursor, bsum, n, etot);
  k_scatter<<<(etot + 255) / 256, 256, 0, stream>>>(ei, cursor, csr, E, n);

  const int gz = (n + 15) / 16;      // gemm grid
  const int ga = (n + 3) / 4;        // agg grid (4 waves/block)

  // layer 1: GAT(8 -> 4x32 concat) + BN + ELU
  k_gemm<8, 128, 4><<<gz, 256, 0, stream>>>(x, W1, as1, ad1, bufA, als, ald, n);
  k_agg<4, 128><<<ga, 256, 0, stream>>>(offs, csr, bufA, als, ald, b1, g1, be1, m1, v1, bufB, n);

  // layer 2: GAT(128 -> 4x32 concat) + BN + ELU
  k_gemm<128, 128, 4><<<gz, 256, 0, stream>>>(bufB, W2, as2, ad2, bufA, als, ald, n);
  k_agg<4, 128><<<ga, 256, 0, stream>>>(offs, csr, bufA, als, ald, b2, g2, be2, m2, v2, bufB, n);

  // layer 3: GAT(128 -> 32, 1 head) + BN + ELU
  k_gemm<128, 32, 1><<<gz, 256, 0, stream>>>(bufB, W3, as3, ad3, bufA, als, ald, n);
  k_agg<1, 32><<<ga, 256, 0, stream>>>(offs, csr, bufA, als, ald, b3, g3, be3, m3, v3, bufB, n);

  // classifier
  k_cls<<<(n + 255) / 256, 256, 0, stream>>>(bufB, cW1, cb1, cW2, cb2, (float*)d_out, n);
}

// Round 2
// 370.856 us; speedup vs baseline: 1.2420x; 1.2420x over previous
//
#include <hip/hip_runtime.h>
#include <hip/hip_bf16.h>

#define BN_EPS 1e-5f

// ---------------- CSR build ----------------

__global__ __launch_bounds__(256) void k_init_counts(int* __restrict__ cnt, int n) {
  int i = blockIdx.x * 256 + threadIdx.x;
  if (i < n) cnt[i] = 1;  // self-loop pre-count
}

__global__ __launch_bounds__(256) void k_hist(const int* __restrict__ ei, int* __restrict__ cnt, int E) {
  int i = blockIdx.x * 256 + threadIdx.x;
  if (i < E) atomicAdd(&cnt[ei[E + i]], 1);  // dst row
}

__global__ __launch_bounds__(256) void k_scan1(const int* __restrict__ cnt, int* __restrict__ offs,
                                               int* __restrict__ bsum, int n) {
  __shared__ int sm[256];
  int tid = threadIdx.x;
  int i = blockIdx.x * 256 + tid;
  int v = (i < n) ? cnt[i] : 0;
  sm[tid] = v;
  __syncthreads();
  #pragma unroll
  for (int off = 1; off < 256; off <<= 1) {
    int t = sm[tid];
    int u = (tid >= off) ? sm[tid - off] : 0;
    __syncthreads();
    sm[tid] = t + u;
    __syncthreads();
  }
  int incl = sm[tid];
  if (i < n) offs[i] = incl - v;          // block-local exclusive
  if (tid == 255) bsum[blockIdx.x] = incl;  // block total
}

__global__ __launch_bounds__(256) void k_scan2(int* __restrict__ bsum, int nb) {
  __shared__ int sm[256];
  int tid = threadIdx.x;
  int v = (tid < nb) ? bsum[tid] : 0;
  sm[tid] = v;
  __syncthreads();
  #pragma unroll
  for (int off = 1; off < 256; off <<= 1) {
    int t = sm[tid];
    int u = (tid >= off) ? sm[tid - off] : 0;
    __syncthreads();
    sm[tid] = t + u;
    __syncthreads();
  }
  if (tid < nb) bsum[tid] = sm[tid] - v;  // exclusive
}

__global__ __launch_bounds__(256) void k_scan3(int* __restrict__ offs, int* __restrict__ cursor,
                                               const int* __restrict__ bsum, int n, int etot) {
  int i = blockIdx.x * 256 + threadIdx.x;
  if (i < n) {
    int o = offs[i] + bsum[i >> 8];
    offs[i] = o;
    cursor[i] = o;
  } else if (i == n) {
    offs[n] = etot;
  }
}

__global__ __launch_bounds__(256) void k_scatter(const int* __restrict__ ei, int* __restrict__ cursor,
                                                 int* __restrict__ csr, int E, int n) {
  int i = blockIdx.x * 256 + threadIdx.x;
  int etot = E + n;
  if (i >= etot) return;
  int s, d;
  if (i < E) { s = ei[i]; d = ei[E + i]; }
  else       { s = i - E; d = s; }        // self-loop
  int pos = atomicAdd(&cursor[d], 1);
  csr[pos] = s;
}

// ---------------- tiled GEMM: H = X @ W, + per-head attention logit dots ----------------
// block tile: 128 rows x FOUT cols, BK k-step, register blocking TM x 8 per thread.

template<int K, int FOUT, int HEADS, int BK>
__global__ __launch_bounds__(256) void k_gemm_t(const float* __restrict__ X,
    const float* __restrict__ W, const float* __restrict__ a_s, const float* __restrict__ a_d,
    float* __restrict__ Hout, float* __restrict__ als, float* __restrict__ ald, int n) {
  constexpr int BM = 128;
  constexpr int CT = FOUT / 8;     // threads along cols (each owns 8 cols)
  constexpr int RT = 256 / CT;     // threads along rows
  constexpr int TM = BM / RT;      // rows per thread
  __shared__ float Xl[BK][BM];     // transposed X tile
  __shared__ float Wl[BK][FOUT];

  int tid = threadIdx.x;
  int ct = tid % CT, rt = tid / CT;
  int row0 = blockIdx.x * BM;

  float acc[TM][8];
  #pragma unroll
  for (int i = 0; i < TM; ++i)
    #pragma unroll
    for (int j = 0; j < 8; ++j) acc[i][j] = 0.f;

  for (int k0 = 0; k0 < K; k0 += BK) {
    // stage X tile (transposed): BM rows x BK cols, float4 along K
    constexpr int TPR = BK / 4;
    for (int s = tid; s < BM * TPR; s += 256) {
      int r = s / TPR, c4 = (s % TPR) * 4;
      float4 v = make_float4(0.f, 0.f, 0.f, 0.f);
      int grow = row0 + r;
      if (grow < n) v = *(const float4*)&X[(size_t)grow * K + k0 + c4];
      Xl[c4 + 0][r] = v.x; Xl[c4 + 1][r] = v.y; Xl[c4 + 2][r] = v.z; Xl[c4 + 3][r] = v.w;
    }
    // stage W tile: BK x FOUT (row-major, contiguous float4)
    for (int s = tid; s < BK * (FOUT / 4); s += 256) {
      int kk = s / (FOUT / 4), c4 = (s % (FOUT / 4)) * 4;
      *(float4*)&Wl[kk][c4] = *(const float4*)&W[(size_t)(k0 + kk) * FOUT + c4];
    }
    __syncthreads();
    #pragma unroll
    for (int kk = 0; kk < BK; ++kk) {
      float b[8], a[TM];
      *(float4*)&b[0] = *(const float4*)&Wl[kk][ct * 8];
      *(float4*)&b[4] = *(const float4*)&Wl[kk][ct * 8 + 4];
      #pragma unroll
      for (int i4 = 0; i4 < TM; i4 += 4)
        *(float4*)&a[i4] = *(const float4*)&Xl[kk][rt * TM + i4];
      #pragma unroll
      for (int i = 0; i < TM; ++i)
        #pragma unroll
        for (int j = 0; j < 8; ++j) acc[i][j] += a[i] * b[j];
    }
    __syncthreads();
  }

  // epilogue: store H, compute attention partial dots, 4-lane reduce
  int col0 = ct * 8;
  int head = (HEADS == 4) ? (col0 >> 5) : 0;
  float asv[8], adv[8];
  #pragma unroll
  for (int j = 0; j < 8; ++j) {
    asv[j] = a_s[head * 32 + ((col0 + j) & 31)];
    adv[j] = a_d[head * 32 + ((col0 + j) & 31)];
  }
  #pragma unroll
  for (int i = 0; i < TM; ++i) {
    int row = row0 + rt * TM + i;
    if (row >= n) break;                 // uniform across the 4-lane reduce group
    float4 o0 = make_float4(acc[i][0], acc[i][1], acc[i][2], acc[i][3]);
    float4 o1 = make_float4(acc[i][4], acc[i][5], acc[i][6], acc[i][7]);
    *(float4*)&Hout[(size_t)row * FOUT + col0] = o0;
    *(float4*)&Hout[(size_t)row * FOUT + col0 + 4] = o1;
    float ps = 0.f, pd = 0.f;
    #pragma unroll
    for (int j = 0; j < 8; ++j) { ps += acc[i][j] * asv[j]; pd += acc[i][j] * adv[j]; }
    ps += __shfl_xor(ps, 1, 64); ps += __shfl_xor(ps, 2, 64);
    pd += __shfl_xor(pd, 1, 64); pd += __shfl_xor(pd, 2, 64);
    if ((ct & 3) == 0) {
      als[row * HEADS + head] = ps;
      ald[row * HEADS + head] = pd;
    }
  }
}

// ---------------- fused edge-softmax + aggregate + bias + BN + ELU ----------------
// one wave per dst node; CSR-gather, no atomics.

template<int HEADS, int FEAT>
__global__ __launch_bounds__(256) void k_agg(const int* __restrict__ offs, const int* __restrict__ csr,
    const float* __restrict__ Hb, const float* __restrict__ als, const float* __restrict__ ald,
    const float* __restrict__ bias, const float* __restrict__ gam, const float* __restrict__ bet,
    const float* __restrict__ mu, const float* __restrict__ var,
    float* __restrict__ Xo, int n) {
  constexpr int LPF = FEAT / 4;   // lanes covering the features (float4 each): 32 or 8
  constexpr int EPW = 64 / LPF;   // edges in flight per wave: 2 or 8
  int wv = (blockIdx.x * 256 + threadIdx.x) >> 6;
  if (wv >= n) return;
  int lane = threadIdx.x & 63;
  int rs = offs[wv], re = offs[wv + 1];

  // phase 1: denominators per head (edge-parallel over lanes)
  float aldv[HEADS];
  #pragma unroll
  for (int h = 0; h < HEADS; ++h) aldv[h] = ald[wv * HEADS + h];
  float den[HEADS];
  #pragma unroll
  for (int h = 0; h < HEADS; ++h) den[h] = 0.f;
  for (int j = rs + lane; j < re; j += 64) {
    int s = csr[j];
    #pragma unroll
    for (int h = 0; h < HEADS; ++h) {
      float e = als[s * HEADS + h] + aldv[h];
      e = (e > 0.f) ? e : 0.2f * e;       // leaky_relu 0.2
      den[h] += __expf(e);
    }
  }
  #pragma unroll
  for (int h = 0; h < HEADS; ++h) {
    float vv = den[h];
    #pragma unroll
    for (int off = 32; off; off >>= 1) vv += __shfl_xor(vv, off, 64);
    den[h] = vv;
  }

  // per-lane head / feature assignment
  int fl = lane % LPF;
  int ei = lane / LPF;
  int f0 = fl * 4;
  int myh = (HEADS == 4) ? (f0 >> 5) : 0;
  float mden = den[0];
  if (HEADS == 4)
    mden = (myh == 0) ? den[0] : ((myh == 1) ? den[1] : ((myh == 2) ? den[2] : den[3]));
  float myinv = 1.f / (mden + 1e-16f);
  float myald = ald[wv * HEADS + myh];

  // phase 2: feature-parallel weighted gather, EPW edges in flight
  float a0 = 0.f, a1 = 0.f, a2 = 0.f, a3 = 0.f;
  for (int j = rs; j < re; j += EPW) {
    int jj = j + ei;
    if (jj < re) {
      int s = csr[jj];
      float e = als[s * HEADS + myh] + myald;
      e = (e > 0.f) ? e : 0.2f * e;
      float alpha = __expf(e) * myinv;
      float4 hv = *(const float4*)(Hb + (size_t)s * FEAT + f0);
      a0 += alpha * hv.x; a1 += alpha * hv.y; a2 += alpha * hv.z; a3 += alpha * hv.w;
    }
  }
  #pragma unroll
  for (int off = 32; off >= LPF; off >>= 1) {
    a0 += __shfl_xor(a0, off, 64);
    a1 += __shfl_xor(a1, off, 64);
    a2 += __shfl_xor(a2, off, 64);
    a3 += __shfl_xor(a3, off, 64);
  }

  if (lane < LPF) {
    float4 o;
    float av[4] = {a0, a1, a2, a3};
    float ov[4];
    #pragma unroll
    for (int q = 0; q < 4; ++q) {
      int f = f0 + q;
      float xo = av[q] + bias[f];
      xo = (xo - mu[f]) * rsqrtf(var[f] + BN_EPS) * gam[f] + bet[f];
      ov[q] = (xo > 0.f) ? xo : (__expf(xo) - 1.f);  // ELU
    }
    o.x = ov[0]; o.y = ov[1]; o.z = ov[2]; o.w = ov[3];
    *(float4*)(Xo + (size_t)wv * FEAT + f0) = o;
  }
}

// ---------------- classifier: Linear(32->16) -> ReLU -> Linear(16->1) -> sigmoid ----------------

__global__ __launch_bounds__(256) void k_cls(const float* __restrict__ X3,
    const float* __restrict__ cW1, const float* __restrict__ cb1,
    const float* __restrict__ cW2, const float* __restrict__ cb2,
    float* __restrict__ out, int n) {
  int i = blockIdx.x * 256 + threadIdx.x;
  if (i >= n) return;
  float x[32];
  #pragma unroll
  for (int k = 0; k < 32; k += 4) {
    float4 v = *(const float4*)&X3[(size_t)i * 32 + k];
    x[k] = v.x; x[k + 1] = v.y; x[k + 2] = v.z; x[k + 3] = v.w;
  }
  float o = cb2[0];
  #pragma unroll
  for (int j = 0; j < 16; ++j) {
    float hs = cb1[j];
    #pragma unroll
    for (int k = 0; k < 32; ++k) hs += x[k] * cW1[k * 16 + j];
    hs = fmaxf(hs, 0.f);
    o += hs * cW2[j];
  }
  out[i] = 1.f / (1.f + __expf(-o));
}

// ---------------- host ----------------

static inline size_t align256(size_t x) { return (x + 255) & ~(size_t)255; }

extern "C" void kernel_launch(void* const* d_in, const int* in_sizes, int n_in,
                              void* d_out, int out_size, void* d_ws, size_t ws_size,
                              hipStream_t stream) {
  const float* x   = (const float*)d_in[0];
  const int*   ei  = (const int*)d_in[1];
  const float* W1  = (const float*)d_in[2];
  const float* as1 = (const float*)d_in[3];
  const float* ad1 = (const float*)d_in[4];
  const float* b1  = (const float*)d_in[5];
  const float* g1  = (const float*)d_in[6];
  const float* be1 = (const float*)d_in[7];
  const float* m1  = (const float*)d_in[8];
  const float* v1  = (const float*)d_in[9];
  const float* W2  = (const float*)d_in[10];
  const float* as2 = (const float*)d_in[11];
  const float* ad2 = (const float*)d_in[12];
  const float* b2  = (const float*)d_in[13];
  const float* g2  = (const float*)d_in[14];
  const float* be2 = (const float*)d_in[15];
  const float* m2  = (const float*)d_in[16];
  const float* v2  = (const float*)d_in[17];
  const float* W3  = (const float*)d_in[18];
  const float* as3 = (const float*)d_in[19];
  const float* ad3 = (const float*)d_in[20];
  const float* b3  = (const float*)d_in[21];
  const float* g3  = (const float*)d_in[22];
  const float* be3 = (const float*)d_in[23];
  const float* m3  = (const float*)d_in[24];
  const float* v3  = (const float*)d_in[25];
  const float* cW1 = (const float*)d_in[26];
  const float* cb1 = (const float*)d_in[27];
  const float* cW2 = (const float*)d_in[28];
  const float* cb2 = (const float*)d_in[29];

  const int n = in_sizes[0] / 8;
  const int E = in_sizes[1] / 2;
  const int etot = E + n;
  const int nb1 = (n + 255) / 256;

  // workspace carve
  char* p = (char*)d_ws;
  int* cursor = (int*)p;  p += align256((size_t)(n + 1) * 4);
  int* offs   = (int*)p;  p += align256((size_t)(n + 1) * 4);
  int* csr    = (int*)p;  p += align256((size_t)etot * 4);
  int* bsum   = (int*)p;  p += align256(1024);
  float* als  = (float*)p; p += align256((size_t)n * 4 * 4);
  float* ald  = (float*)p; p += align256((size_t)n * 4 * 4);
  float* bufA = (float*)p; p += align256((size_t)n * 128 * 4);
  float* bufB = (float*)p; p += align256((size_t)n * 128 * 4);

  // CSR build
  k_init_counts<<<nb1, 256, 0, stream>>>(cursor, n);
  k_hist<<<(E + 255) / 256, 256, 0, stream>>>(ei, cursor, E);
  k_scan1<<<nb1, 256, 0, stream>>>(cursor, offs, bsum, n);
  k_scan2<<<1, 256, 0, stream>>>(bsum, nb1);
  k_scan3<<<(n + 1 + 255) / 256, 256, 0, stream>>>(offs, cursor, bsum, n, etot);
  k_scatter<<<(etot + 255) / 256, 256, 0, stream>>>(ei, cursor, csr, E, n);

  const int gt = (n + 127) / 128;    // tiled gemm grid
  const int ga = (n + 3) / 4;        // agg grid (4 waves/block)

  // layer 1: GAT(8 -> 4x32 concat) + BN + ELU
  k_gemm_t<8, 128, 4, 8><<<gt, 256, 0, stream>>>(x, W1, as1, ad1, bufA, als, ald, n);
  k_agg<4, 128><<<ga, 256, 0, stream>>>(offs, csr, bufA, als, ald, b1, g1, be1, m1, v1, bufB, n);

  // layer 2: GAT(128 -> 4x32 concat) + BN + ELU
  k_gemm_t<128, 128, 4, 16><<<gt, 256, 0, stream>>>(bufB, W2, as2, ad2, bufA, als, ald, n);
  k_agg<4, 128><<<ga, 256, 0, stream>>>(offs, csr, bufA, als, ald, b2, g2, be2, m2, v2, bufB, n);

  // layer 3: GAT(128 -> 32, 1 head) + BN + ELU
  k_gemm_t<128, 32, 1, 16><<<gt, 256, 0, stream>>>(bufB, W3, as3, ad3, bufA, als, ald, n);
  k_agg<1, 32><<<ga, 256, 0, stream>>>(offs, csr, bufA, als, ald, b3, g3, be3, m3, v3, bufB, n);

  // classifier
  k_cls<<<(n + 255) / 256, 256, 0, stream>>>(bufB, cW1, cb1, cW2, cb2, (float*)d_out, n);
}

// Round 3
// 340.515 us; speedup vs baseline: 1.3527x; 1.0891x over previous
//
#include <hip/hip_runtime.h>
#include <hip/hip_bf16.h>

#define BN_EPS 1e-5f

// ---------------- CSR build ----------------

__global__ __launch_bounds__(256) void k_init_counts(int* __restrict__ cnt, int n) {
  int i = blockIdx.x * 256 + threadIdx.x;
  if (i < n) cnt[i] = 1;  // self-loop pre-count
}

__global__ __launch_bounds__(256) void k_hist(const int* __restrict__ ei, int* __restrict__ cnt, int E) {
  int i = blockIdx.x * 256 + threadIdx.x;
  if (i < E) atomicAdd(&cnt[ei[E + i]], 1);  // dst row
}

__global__ __launch_bounds__(256) void k_scan1(const int* __restrict__ cnt, int* __restrict__ offs,
                                               int* __restrict__ bsum, int n) {
  __shared__ int sm[256];
  int tid = threadIdx.x;
  int i = blockIdx.x * 256 + tid;
  int v = (i < n) ? cnt[i] : 0;
  sm[tid] = v;
  __syncthreads();
  #pragma unroll
  for (int off = 1; off < 256; off <<= 1) {
    int t = sm[tid];
    int u = (tid >= off) ? sm[tid - off] : 0;
    __syncthreads();
    sm[tid] = t + u;
    __syncthreads();
  }
  int incl = sm[tid];
  if (i < n) offs[i] = incl - v;          // block-local exclusive
  if (tid == 255) bsum[blockIdx.x] = incl;  // block total
}

__global__ __launch_bounds__(256) void k_scan2(int* __restrict__ bsum, int nb) {
  __shared__ int sm[256];
  int tid = threadIdx.x;
  int v = (tid < nb) ? bsum[tid] : 0;
  sm[tid] = v;
  __syncthreads();
  #pragma unroll
  for (int off = 1; off < 256; off <<= 1) {
    int t = sm[tid];
    int u = (tid >= off) ? sm[tid - off] : 0;
    __syncthreads();
    sm[tid] = t + u;
    __syncthreads();
  }
  if (tid < nb) bsum[tid] = sm[tid] - v;  // exclusive
}

__global__ __launch_bounds__(256) void k_scan3(int* __restrict__ offs, int* __restrict__ cursor,
                                               const int* __restrict__ bsum, int n, int etot) {
  int i = blockIdx.x * 256 + threadIdx.x;
  if (i < n) {
    int o = offs[i] + bsum[i >> 8];
    offs[i] = o;
    cursor[i] = o;
  } else if (i == n) {
    offs[n] = etot;
  }
}

__global__ __launch_bounds__(256) void k_scatter(const int* __restrict__ ei, int* __restrict__ cursor,
                                                 int* __restrict__ csr, int E, int n) {
  int i = blockIdx.x * 256 + threadIdx.x;
  int etot = E + n;
  if (i >= etot) return;
  int s, d;
  if (i < E) { s = ei[i]; d = ei[E + i]; }
  else       { s = i - E; d = s; }        // self-loop
  int pos = atomicAdd(&cursor[d], 1);
  csr[pos] = s;
}

// ---------------- tiled GEMM: H = X @ W, + per-head attention logit dots ----------------

template<int K, int FOUT, int HEADS, int BK>
__global__ __launch_bounds__(256) void k_gemm_t(const float* __restrict__ X,
    const float* __restrict__ W, const float* __restrict__ a_s, const float* __restrict__ a_d,
    float* __restrict__ Hout, float* __restrict__ als, float* __restrict__ ald, int n) {
  constexpr int BM = 128;
  constexpr int CT = FOUT / 8;     // threads along cols (each owns 8 cols)
  constexpr int RT = 256 / CT;     // threads along rows
  constexpr int TM = BM / RT;      // rows per thread
  __shared__ float Xl[BK][BM];     // transposed X tile
  __shared__ float Wl[BK][FOUT];

  int tid = threadIdx.x;
  int ct = tid % CT, rt = tid / CT;
  int row0 = blockIdx.x * BM;

  float acc[TM][8];
  #pragma unroll
  for (int i = 0; i < TM; ++i)
    #pragma unroll
    for (int j = 0; j < 8; ++j) acc[i][j] = 0.f;

  for (int k0 = 0; k0 < K; k0 += BK) {
    constexpr int TPR = BK / 4;
    for (int s = tid; s < BM * TPR; s += 256) {
      int r = s / TPR, c4 = (s % TPR) * 4;
      float4 v = make_float4(0.f, 0.f, 0.f, 0.f);
      int grow = row0 + r;
      if (grow < n) v = *(const float4*)&X[(size_t)grow * K + k0 + c4];
      Xl[c4 + 0][r] = v.x; Xl[c4 + 1][r] = v.y; Xl[c4 + 2][r] = v.z; Xl[c4 + 3][r] = v.w;
    }
    for (int s = tid; s < BK * (FOUT / 4); s += 256) {
      int kk = s / (FOUT / 4), c4 = (s % (FOUT / 4)) * 4;
      *(float4*)&Wl[kk][c4] = *(const float4*)&W[(size_t)(k0 + kk) * FOUT + c4];
    }
    __syncthreads();
    #pragma unroll
    for (int kk = 0; kk < BK; ++kk) {
      float b[8], a[TM];
      *(float4*)&b[0] = *(const float4*)&Wl[kk][ct * 8];
      *(float4*)&b[4] = *(const float4*)&Wl[kk][ct * 8 + 4];
      #pragma unroll
      for (int i4 = 0; i4 < TM; i4 += 4)
        *(float4*)&a[i4] = *(const float4*)&Xl[kk][rt * TM + i4];
      #pragma unroll
      for (int i = 0; i < TM; ++i)
        #pragma unroll
        for (int j = 0; j < 8; ++j) acc[i][j] += a[i] * b[j];
    }
    __syncthreads();
  }

  int col0 = ct * 8;
  int head = (HEADS == 4) ? (col0 >> 5) : 0;
  float asv[8], adv[8];
  #pragma unroll
  for (int j = 0; j < 8; ++j) {
    asv[j] = a_s[head * 32 + ((col0 + j) & 31)];
    adv[j] = a_d[head * 32 + ((col0 + j) & 31)];
  }
  #pragma unroll
  for (int i = 0; i < TM; ++i) {
    int row = row0 + rt * TM + i;
    if (row >= n) break;                 // uniform across the 4-lane reduce group
    float4 o0 = make_float4(acc[i][0], acc[i][1], acc[i][2], acc[i][3]);
    float4 o1 = make_float4(acc[i][4], acc[i][5], acc[i][6], acc[i][7]);
    *(float4*)&Hout[(size_t)row * FOUT + col0] = o0;
    *(float4*)&Hout[(size_t)row * FOUT + col0 + 4] = o1;
    float ps = 0.f, pd = 0.f;
    #pragma unroll
    for (int j = 0; j < 8; ++j) { ps += acc[i][j] * asv[j]; pd += acc[i][j] * adv[j]; }
    ps += __shfl_xor(ps, 1, 64); ps += __shfl_xor(ps, 2, 64);
    pd += __shfl_xor(pd, 1, 64); pd += __shfl_xor(pd, 2, 64);
    if ((ct & 3) == 0) {
      als[row * HEADS + head] = ps;
      ald[row * HEADS + head] = pd;
    }
  }
}

// ---------------- fused edge-softmax + aggregate + bias + BN + ELU ----------------
// one wave per dst node; CSR-gather, no atomics.
// Phase 1 stages (src, exp) in per-wave LDS so phase 2's gather addresses come
// from LDS (no global dependency chain); phase 2 batches 4 gathers in flight.

template<int HEADS, int FEAT>
__global__ __launch_bounds__(256) void k_agg(const int* __restrict__ offs, const int* __restrict__ csr,
    const float* __restrict__ Hb, const float* __restrict__ als, const float* __restrict__ ald,
    const float* __restrict__ bias, const float* __restrict__ gam, const float* __restrict__ bet,
    const float* __restrict__ mu, const float* __restrict__ var,
    float* __restrict__ Xo, int n) {
  constexpr int LPF = FEAT / 4;   // lanes covering the features (float4 each): 32 or 8
  constexpr int EPW = 64 / LPF;   // edges in flight per wave: 2 or 8
  constexpr int CAP = 128;        // LDS-staged edges per node (deg>CAP: cold fallback)
  constexpr int UB = 4;           // gather batch depth
  __shared__ int   s_idx[4][CAP];
  __shared__ float s_exp[4][CAP * HEADS];
  int wslot = threadIdx.x >> 6;
  int wv = (blockIdx.x * 256 + threadIdx.x) >> 6;
  if (wv >= n) return;            // no __syncthreads below; LDS is per-wave
  int lane = threadIdx.x & 63;
  int rs = offs[wv], re = offs[wv + 1];
  int deg = re - rs;

  float aldv[HEADS];
  #pragma unroll
  for (int h = 0; h < HEADS; ++h) aldv[h] = ald[wv * HEADS + h];

  // phase 1: denominators per head; stage (src, exp) in LDS
  float den[HEADS];
  #pragma unroll
  for (int h = 0; h < HEADS; ++h) den[h] = 0.f;
  for (int j = lane; j < deg; j += 64) {
    int s = csr[rs + j];
    bool st = (j < CAP);
    if (st) s_idx[wslot][j] = s;
    #pragma unroll
    for (int h = 0; h < HEADS; ++h) {
      float e = als[s * HEADS + h] + aldv[h];
      e = (e > 0.f) ? e : 0.2f * e;       // leaky_relu 0.2
      float ex = __expf(e);
      den[h] += ex;
      if (st) s_exp[wslot][j * HEADS + h] = ex;
    }
  }
  #pragma unroll
  for (int h = 0; h < HEADS; ++h) {
    float vv = den[h];
    #pragma unroll
    for (int off = 32; off; off >>= 1) vv += __shfl_xor(vv, off, 64);
    den[h] = vv;
  }

  // per-lane head / feature assignment
  int fl = lane % LPF;
  int ei = lane / LPF;
  int f0 = fl * 4;
  int myh = (HEADS == 4) ? (f0 >> 5) : 0;
  float mden = den[0];
  if (HEADS == 4)
    mden = (myh == 0) ? den[0] : ((myh == 1) ? den[1] : ((myh == 2) ? den[2] : den[3]));
  float myinv = 1.f / (mden + 1e-16f);

  // phase 2: feature-parallel weighted gather, UB*EPW edges in flight per wave
  float a0 = 0.f, a1 = 0.f, a2 = 0.f, a3 = 0.f;
  int dstage = deg < CAP ? deg : CAP;
  for (int j0 = ei; j0 < dstage; j0 += EPW * UB) {
    float4 hv[UB];
    float  al[UB];
    #pragma unroll
    for (int u = 0; u < UB; ++u) {
      int j = j0 + u * EPW;
      int jc = (j < dstage) ? j : (dstage - 1);       // clamp: tail loads broadcast
      int s = s_idx[wslot][jc];
      al[u] = (j < dstage) ? s_exp[wslot][jc * HEADS + myh] * myinv : 0.f;
      hv[u] = *(const float4*)(Hb + (size_t)s * FEAT + f0);
    }
    #pragma unroll
    for (int u = 0; u < UB; ++u) {
      a0 += al[u] * hv[u].x; a1 += al[u] * hv[u].y;
      a2 += al[u] * hv[u].z; a3 += al[u] * hv[u].w;
    }
  }
  if (deg > CAP) {  // cold path, recompute inline
    float myald = aldv[0];
    if (HEADS == 4)
      myald = (myh == 0) ? aldv[0] : ((myh == 1) ? aldv[1] : ((myh == 2) ? aldv[2] : aldv[3]));
    for (int j = CAP + ei; j < deg; j += EPW) {
      int s = csr[rs + j];
      float e = als[s * HEADS + myh] + myald;
      e = (e > 0.f) ? e : 0.2f * e;
      float alpha = __expf(e) * myinv;
      float4 hv = *(const float4*)(Hb + (size_t)s * FEAT + f0);
      a0 += alpha * hv.x; a1 += alpha * hv.y; a2 += alpha * hv.z; a3 += alpha * hv.w;
    }
  }
  #pragma unroll
  for (int off = 32; off >= LPF; off >>= 1) {
    a0 += __shfl_xor(a0, off, 64);
    a1 += __shfl_xor(a1, off, 64);
    a2 += __shfl_xor(a2, off, 64);
    a3 += __shfl_xor(a3, off, 64);
  }

  if (lane < LPF) {
    float4 o;
    float av[4] = {a0, a1, a2, a3};
    float ov[4];
    #pragma unroll
    for (int q = 0; q < 4; ++q) {
      int f = f0 + q;
      float xo = av[q] + bias[f];
      xo = (xo - mu[f]) * rsqrtf(var[f] + BN_EPS) * gam[f] + bet[f];
      ov[q] = (xo > 0.f) ? xo : (__expf(xo) - 1.f);  // ELU
    }
    o.x = ov[0]; o.y = ov[1]; o.z = ov[2]; o.w = ov[3];
    *(float4*)(Xo + (size_t)wv * FEAT + f0) = o;
  }
}

// ---------------- classifier: Linear(32->16) -> ReLU -> Linear(16->1) -> sigmoid ----------------

__global__ __launch_bounds__(256) void k_cls(const float* __restrict__ X3,
    const float* __restrict__ cW1, const float* __restrict__ cb1,
    const float* __restrict__ cW2, const float* __restrict__ cb2,
    float* __restrict__ out, int n) {
  int i = blockIdx.x * 256 + threadIdx.x;
  if (i >= n) return;
  float x[32];
  #pragma unroll
  for (int k = 0; k < 32; k += 4) {
    float4 v = *(const float4*)&X3[(size_t)i * 32 + k];
    x[k] = v.x; x[k + 1] = v.y; x[k + 2] = v.z; x[k + 3] = v.w;
  }
  float o = cb2[0];
  #pragma unroll
  for (int j = 0; j < 16; ++j) {
    float hs = cb1[j];
    #pragma unroll
    for (int k = 0; k < 32; ++k) hs += x[k] * cW1[k * 16 + j];
    hs = fmaxf(hs, 0.f);
    o += hs * cW2[j];
  }
  out[i] = 1.f / (1.f + __expf(-o));
}

// ---------------- host ----------------

static inline size_t align256(size_t x) { return (x + 255) & ~(size_t)255; }

extern "C" void kernel_launch(void* const* d_in, const int* in_sizes, int n_in,
                              void* d_out, int out_size, void* d_ws, size_t ws_size,
                              hipStream_t stream) {
  const float* x   = (const float*)d_in[0];
  const int*   ei  = (const int*)d_in[1];
  const float* W1  = (const float*)d_in[2];
  const float* as1 = (const float*)d_in[3];
  const float* ad1 = (const float*)d_in[4];
  const float* b1  = (const float*)d_in[5];
  const float* g1  = (const float*)d_in[6];
  const float* be1 = (const float*)d_in[7];
  const float* m1  = (const float*)d_in[8];
  const float* v1  = (const float*)d_in[9];
  const float* W2  = (const float*)d_in[10];
  const float* as2 = (const float*)d_in[11];
  const float* ad2 = (const float*)d_in[12];
  const float* b2  = (const float*)d_in[13];
  const float* g2  = (const float*)d_in[14];
  const float* be2 = (const float*)d_in[15];
  const float* m2  = (const float*)d_in[16];
  const float* v2  = (const float*)d_in[17];
  const float* W3  = (const float*)d_in[18];
  const float* as3 = (const float*)d_in[19];
  const float* ad3 = (const float*)d_in[20];
  const float* b3  = (const float*)d_in[21];
  const float* g3  = (const float*)d_in[22];
  const float* be3 = (const float*)d_in[23];
  const float* m3  = (const float*)d_in[24];
  const float* v3  = (const float*)d_in[25];
  const float* cW1 = (const float*)d_in[26];
  const float* cb1 = (const float*)d_in[27];
  const float* cW2 = (const float*)d_in[28];
  const float* cb2 = (const float*)d_in[29];

  const int n = in_sizes[0] / 8;
  const int E = in_sizes[1] / 2;
  const int etot = E + n;
  const int nb1 = (n + 255) / 256;

  // workspace carve
  char* p = (char*)d_ws;
  int* cursor = (int*)p;  p += align256((size_t)(n + 1) * 4);
  int* offs   = (int*)p;  p += align256((size_t)(n + 1) * 4);
  int* csr    = (int*)p;  p += align256((size_t)etot * 4);
  int* bsum   = (int*)p;  p += align256(1024);
  float* als  = (float*)p; p += align256((size_t)n * 4 * 4);
  float* ald  = (float*)p; p += align256((size_t)n * 4 * 4);
  float* bufA = (float*)p; p += align256((size_t)n * 128 * 4);
  float* bufB = (float*)p; p += align256((size_t)n * 128 * 4);

  // CSR build
  k_init_counts<<<nb1, 256, 0, stream>>>(cursor, n);
  k_hist<<<(E + 255) / 256, 256, 0, stream>>>(ei, cursor, E);
  k_scan1<<<nb1, 256, 0, stream>>>(cursor, offs, bsum, n);
  k_scan2<<<1, 256, 0, stream>>>(bsum, nb1);
  k_scan3<<<(n + 1 + 255) / 256, 256, 0, stream>>>(offs, cursor, bsum, n, etot);
  k_scatter<<<(etot + 255) / 256, 256, 0, stream>>>(ei, cursor, csr, E, n);

  const int gt = (n + 127) / 128;    // tiled gemm grid
  const int ga = (n + 3) / 4;        // agg grid (4 waves/block)

  // layer 1: GAT(8 -> 4x32 concat) + BN + ELU
  k_gemm_t<8, 128, 4, 8><<<gt, 256, 0, stream>>>(x, W1, as1, ad1, bufA, als, ald, n);
  k_agg<4, 128><<<ga, 256, 0, stream>>>(offs, csr, bufA, als, ald, b1, g1, be1, m1, v1, bufB, n);

  // layer 2: GAT(128 -> 4x32 concat) + BN + ELU
  k_gemm_t<128, 128, 4, 16><<<gt, 256, 0, stream>>>(bufB, W2, as2, ad2, bufA, als, ald, n);
  k_agg<4, 128><<<ga, 256, 0, stream>>>(offs, csr, bufA, als, ald, b2, g2, be2, m2, v2, bufB, n);

  // layer 3: GAT(128 -> 32, 1 head) + BN + ELU
  k_gemm_t<128, 32, 1, 16><<<gt, 256, 0, stream>>>(bufB, W3, as3, ad3, bufA, als, ald, n);
  k_agg<1, 32><<<ga, 256, 0, stream>>>(offs, csr, bufA, als, ald, b3, g3, be3, m3, v3, bufB, n);

  // classifier
  k_cls<<<(n + 255) / 256, 256, 0, stream>>>(bufB, cW1, cb1, cW2, cb2, (float*)d_out, n);
}